// Round 3
// baseline (7106.944 us; speedup 1.0000x reference)
//
#include <hip/hip_runtime.h>

#define TT 512
#define BB 64
#define II 512
#define LL 1024
#define NWG 64

typedef __bf16 bf16x8 __attribute__((ext_vector_type(8)));
typedef float f32x4 __attribute__((ext_vector_type(4)));
typedef float f32x2 __attribute__((ext_vector_type(2)));
typedef unsigned long long u64x2 __attribute__((ext_vector_type(2)));

// ---------- workspace layout (bytes) ----------
// wsWi : Wi frag-ordered bf16 [8 bn][16 ks][8 nsub][64 lane][8e]  = 1 MiB
// wsWh : Wh frag-ordered bf16 [64 wg][32 ks][64 lane][8e]         = 2 MiB
// hbuf : ping-pong H row-major bf16  2 x [64][1024]               = 256 KiB
// flags: 64 words (per-WG arrival epoch)
#define WSWI_OFF 0u
#define WSWH_OFF (1u << 20)
#define HBUF_OFF (3u << 20)
#define FLAG_OFF ((3u << 20) + (1u << 18))

__device__ __forceinline__ unsigned short f2bf(float f) {
  unsigned int u = __builtin_bit_cast(unsigned int, f);
  u += 0x7fffu + ((u >> 16) & 1u);   // round-to-nearest-even (inputs finite)
  return (unsigned short)(u >> 16);
}

__device__ __forceinline__ bf16x8 ld_frag(const unsigned short* p) {
  return __builtin_bit_cast(bf16x8, *(const uint4*)p);
}

// device-coherent (agent-scope, sc1) 16B load: bypasses stale per-XCD L2
__device__ __forceinline__ bf16x8 ld_h16(const unsigned short* p) {
  const unsigned long long* q = (const unsigned long long*)p;
  u64x2 v;
  v[0] = __hip_atomic_load(q, __ATOMIC_RELAXED, __HIP_MEMORY_SCOPE_AGENT);
  v[1] = __hip_atomic_load(q + 1, __ATOMIC_RELAXED, __HIP_MEMORY_SCOPE_AGENT);
  return __builtin_bit_cast(bf16x8, v);
}

__device__ __forceinline__ void st_h8(unsigned short* p, unsigned long long v) {
  __hip_atomic_store((unsigned long long*)p, v, __ATOMIC_RELAXED,
                     __HIP_MEMORY_SCOPE_AGENT);
}

// ============================================================
// prep: frag-order Wi/Wh, row-major bf16 h0, zero flags.
// ============================================================
__global__ __launch_bounds__(256) void prep_kernel(
    const float* __restrict__ h0, const float* __restrict__ Wi,
    const float* __restrict__ Wh, unsigned short* __restrict__ wsWi,
    unsigned short* __restrict__ wsWh, unsigned short* __restrict__ hbuf,
    unsigned int* __restrict__ flags) {
  int idx = blockIdx.x * 256 + threadIdx.x;
  if (idx < 64) flags[idx] = 0u;
  const float* src;
  unsigned short* dst;
  if (idx < 65536) {                       // Wi slots
    int ln = idx & 63, s = idx >> 6;
    int nsub = s & 7, s2 = s >> 3, ks = s2 & 15, bn = s2 >> 4;
    int n = bn * 128 + nsub * 16 + (ln & 15);
    int k = ks * 32 + (ln >> 4) * 8;
    src = Wi + (size_t)n * II + k;
    dst = wsWi + (size_t)idx * 8;
  } else if (idx < 196608) {               // Wh slots
    int o = idx - 65536;
    int ln = o & 63, s = o >> 6, ks = s & 31, wg = s >> 5;
    int col = wg * 16 + (ln & 15);
    int k = ks * 32 + (ln >> 4) * 8;
    src = Wh + (size_t)col * LL + k;
    dst = wsWh + (size_t)o * 8;
  } else if (idx < 204800) {               // h0 slots (row-major identity)
    int o = idx - 196608;
    src = h0 + (size_t)o * 8;
    dst = hbuf + (size_t)o * 8;
  } else {
    return;
  }
  float4 a0 = *(const float4*)src;
  float4 a1 = *(const float4*)(src + 4);
  uint4 p;
  p.x = f2bf(a0.x) | ((unsigned)f2bf(a0.y) << 16);
  p.y = f2bf(a0.z) | ((unsigned)f2bf(a0.w) << 16);
  p.z = f2bf(a1.x) | ((unsigned)f2bf(a1.y) << 16);
  p.w = f2bf(a1.z) | ((unsigned)f2bf(a1.w) << 16);
  *(uint4*)dst = p;
}

// ============================================================
// xi = x @ Wi^T + bi  -> d_out (reused as xi buffer)
// ============================================================
__global__ __launch_bounds__(256) void xi_gemm(
    const float* __restrict__ x, const float* __restrict__ bi,
    const unsigned short* __restrict__ wsWi, float* __restrict__ out) {
  __shared__ unsigned short As[8 * 64 * 8];
  __shared__ unsigned short Bs[8 * 64 * 8];
  const int tid = threadIdx.x;
  const int ln = tid & 63;
  const int wv = tid >> 6;
  const int wm = wv >> 1, wn = wv & 1;
  const int bn = blockIdx.x;
  const int Mbase = blockIdx.y * 128;
  const int Nbase = bn * 128;

  f32x4 acc[4][4] = {};

  for (int ks = 0; ks < 16; ++ks) {
    __syncthreads();
#pragma unroll
    for (int i = 0; i < 2; ++i) {
      int slot = tid + 256 * i;
      int msub = slot >> 6;
      int l2 = slot & 63;
      const float* src =
          x + (size_t)(Mbase + msub * 16 + (l2 & 15)) * II + ks * 32 + (l2 >> 4) * 8;
      float4 a0 = *(const float4*)src;
      float4 a1 = *(const float4*)(src + 4);
      uint4 p;
      p.x = f2bf(a0.x) | ((unsigned)f2bf(a0.y) << 16);
      p.y = f2bf(a0.z) | ((unsigned)f2bf(a0.w) << 16);
      p.z = f2bf(a1.x) | ((unsigned)f2bf(a1.y) << 16);
      p.w = f2bf(a1.z) | ((unsigned)f2bf(a1.w) << 16);
      *(uint4*)(As + slot * 8) = p;
      const uint4* bsrc = (const uint4*)(wsWi + (size_t)(bn * 16 + ks) * 4096) + slot;
      *(uint4*)(Bs + slot * 8) = *bsrc;
    }
    __syncthreads();
    bf16x8 af[4];
#pragma unroll
    for (int m = 0; m < 4; ++m)
      af[m] = ld_frag(As + ((wm * 4 + m) * 64 + ln) * 8);
#pragma unroll
    for (int n = 0; n < 4; ++n) {
      bf16x8 bf = ld_frag(Bs + ((wn * 4 + n) * 64 + ln) * 8);
#pragma unroll
      for (int m = 0; m < 4; ++m)
        acc[m][n] = __builtin_amdgcn_mfma_f32_16x16x32_bf16(af[m], bf, acc[m][n], 0, 0, 0);
    }
  }
#pragma unroll
  for (int n = 0; n < 4; ++n) {
    int col = Nbase + wn * 64 + n * 16 + (ln & 15);
    float bv = bi[col];
#pragma unroll
    for (int m = 0; m < 4; ++m) {
      int row0 = Mbase + wm * 64 + m * 16 + (ln >> 4) * 4;
#pragma unroll
      for (int r = 0; r < 4; ++r)
        out[(size_t)(row0 + r) * LL + col] = acc[m][n][r] + bv;
    }
  }
}

// ============================================================
// Persistent scan: 64 WGs x 512 thr, WG owns 16 cols.
// Pure-C device-coherent (agent-scope) atomics for H + flags.
// No fences, no L2 invalidation, no inline asm.
// ============================================================
__global__ __launch_bounds__(512) void scan_kernel(
    const unsigned short* __restrict__ wsWh, float* __restrict__ out,
    unsigned short* __restrict__ hbuf, unsigned int* __restrict__ flags) {
  __shared__ unsigned short Bfrag[32 * 64 * 8];       // 32 KiB
  __shared__ f32x4 red[8][4][64];                     // 32 KiB
  __shared__ float xiT[64][16];                       // 4 KiB
  __shared__ __align__(16) float Tt[4][16][20];       // 5 KiB
  const int tid = threadIdx.x;
  const int ln = tid & 63;
  const int wv = tid >> 6;   // 0..7
  const int wg = blockIdx.x; // 0..63

  { // load this WG's Wh fragment slice once
    const uint4* src = (const uint4*)(wsWh + (size_t)wg * 32 * 64 * 8);
    uint4* dst = (uint4*)Bfrag;
#pragma unroll
    for (int i = 0; i < 4; ++i) dst[tid + 512 * i] = src[tid + 512 * i];
  }
  __syncthreads();

  for (int t = 0; t < TT; ++t) {
    // ---- wait: all WGs must have published step t-1 (relaxed sc1 poll) ----
    if (t > 0) {
      unsigned f;
      do {
        f = __hip_atomic_load(flags + ln, __ATOMIC_RELAXED, __HIP_MEMORY_SCOPE_AGENT);
      } while (__all((int)f >= t) == 0);
    }
    __builtin_amdgcn_sched_barrier(0);

    const unsigned short* hcur = hbuf + (size_t)(t & 1) * 65536;

    // ---- H fragment loads (device-coherent, bypass stale L2) ----
    bf16x8 hf[4][4];
#pragma unroll
    for (int m = 0; m < 4; ++m) {
      const unsigned short* base =
          hcur + ((m * 16 + (ln & 15)) * 1024 + wv * 128 + (ln >> 4) * 8);
#pragma unroll
      for (int kk = 0; kk < 4; ++kk)
        hf[m][kk] = ld_h16(base + kk * 32);
    }
    // ---- xi load (plain cached; compiler may hoist, harmless) ----
    f32x2 xv = *(const f32x2*)(out + (size_t)t * 65536 +
                               (size_t)(tid >> 3) * 1024 + wg * 16 + (tid & 7) * 2);

    // ---- MFMA: 4 m-tiles x this wave's 128-wide K slice ----
    f32x4 acc[4] = {};
#pragma unroll
    for (int kk = 0; kk < 4; ++kk) {
      int ks = wv * 4 + kk;
      bf16x8 bf = ld_frag(Bfrag + (ks * 64 + ln) * 8);
#pragma unroll
      for (int m = 0; m < 4; ++m)
        acc[m] = __builtin_amdgcn_mfma_f32_16x16x32_bf16(hf[m][kk], bf, acc[m], 0, 0, 0);
    }

    *(f32x2*)&xiT[tid >> 3][(tid & 7) * 2] = xv;
#pragma unroll
    for (int m = 0; m < 4; ++m) red[wv][m][ln] = acc[m];
    __syncthreads();

    unsigned short* hnext = hbuf + (size_t)((t + 1) & 1) * 65536;
    if (wv < 4) {
      const int m = wv, col16 = ln & 15, rq = ln >> 4;
      f32x4 s = red[0][m][ln];
#pragma unroll
      for (int kh = 1; kh < 8; ++kh) s += red[kh][m][ln];
#pragma unroll
      for (int r = 0; r < 4; ++r) {
        int row16 = rq * 4 + r;
        Tt[m][row16][col16] = tanhf(s[r] + xiT[m * 16 + row16][col16]);
      }
      // out fp32: one nontemporal dwordx4 per lane (row ln>>2, col-quad ln&3)
      {
        f32x4 o = *(const f32x4*)&Tt[m][ln >> 2][(ln & 3) * 4];
        __builtin_nontemporal_store(
            o, (f32x4*)(out + (size_t)t * 65536 +
                        (size_t)(m * 16 + (ln >> 2)) * 1024 + wg * 16 + (ln & 3) * 4));
      }
      // h bf16: one device-coherent u64 per lane (4 values)
      {
        const float* sp = &Tt[m][ln >> 2][(ln & 3) * 4];
        unsigned long long pv =
            (unsigned long long)(f2bf(sp[0]) | ((unsigned)f2bf(sp[1]) << 16)) |
            ((unsigned long long)(f2bf(sp[2]) | ((unsigned)f2bf(sp[3]) << 16)) << 32);
        st_h8(hnext + (size_t)(m * 16 + (ln >> 2)) * 1024 + wg * 16 + (ln & 3) * 4, pv);
      }
    }
    // barrier drains each wave's outstanding stores (vmcnt(0)) before release
    __syncthreads();
    if (tid == 0)
      __hip_atomic_store(flags + wg, (unsigned)(t + 1), __ATOMIC_RELEASE,
                         __HIP_MEMORY_SCOPE_AGENT);
  }
}

extern "C" void kernel_launch(void* const* d_in, const int* in_sizes, int n_in,
                              void* d_out, int out_size, void* d_ws, size_t ws_size,
                              hipStream_t stream) {
  const float* x  = (const float*)d_in[0];
  const float* h0 = (const float*)d_in[1];
  const float* Wi = (const float*)d_in[2];
  const float* bi = (const float*)d_in[3];
  const float* Wh = (const float*)d_in[4];
  float* out = (float*)d_out;
  char* ws = (char*)d_ws;
  unsigned short* wsWi = (unsigned short*)(ws + WSWI_OFF);
  unsigned short* wsWh = (unsigned short*)(ws + WSWH_OFF);
  unsigned short* hbuf = (unsigned short*)(ws + HBUF_OFF);
  unsigned int* flags = (unsigned int*)(ws + FLAG_OFF);

  prep_kernel<<<800, 256, 0, stream>>>(h0, Wi, Wh, wsWi, wsWh, hbuf, flags);
  xi_gemm<<<dim3(8, 256), 256, 0, stream>>>(x, bi, wsWi, out);
  void* args[] = {(void*)&wsWh, (void*)&out, (void*)&hbuf, (void*)&flags};
  hipLaunchCooperativeKernel(reinterpret_cast<void*>(scan_kernel), dim3(NWG),
                             dim3(512), args, 0, stream);
}

// Round 5
// 4030.580 us; speedup vs baseline: 1.7633x; 1.7633x over previous
//
#include <hip/hip_runtime.h>

#define TT 512
#define BB 64
#define II 512
#define LL 1024
#define NWG 64

typedef __bf16 bf16x8 __attribute__((ext_vector_type(8)));
typedef float f32x4 __attribute__((ext_vector_type(4)));
typedef unsigned int u32x4 __attribute__((ext_vector_type(4)));

// ---------- workspace layout (bytes) ----------
// wsWi : Wi frag-ordered bf16 [8 bn][16 ks][8 nsub][64 lane][8e]  = 1 MiB
// wsWh : Wh frag-ordered bf16 [64 wg][32 ks][64 lane][8e]         = 2 MiB
// hbuf : ping-pong H row-major bf16  2 x [64][1024]               = 256 KiB
// flags: 64 words (per-WG arrival epoch)
#define WSWI_OFF 0u
#define WSWH_OFF (1u << 20)
#define HBUF_OFF (3u << 20)
#define FLAG_OFF ((3u << 20) + (1u << 18))

__device__ __forceinline__ unsigned short f2bf(float f) {
  unsigned int u = __builtin_bit_cast(unsigned int, f);
  u += 0x7fffu + ((u >> 16) & 1u);   // round-to-nearest-even (inputs finite)
  return (unsigned short)(u >> 16);
}

__device__ __forceinline__ bf16x8 ld_frag(const unsigned short* p) {
  return __builtin_bit_cast(bf16x8, *(const uint4*)p);
}

// ============================================================
// prep: frag-order Wi/Wh, row-major bf16 h0, zero flags.
// ============================================================
__global__ __launch_bounds__(256) void prep_kernel(
    const float* __restrict__ h0, const float* __restrict__ Wi,
    const float* __restrict__ Wh, unsigned short* __restrict__ wsWi,
    unsigned short* __restrict__ wsWh, unsigned short* __restrict__ hbuf,
    unsigned int* __restrict__ flags) {
  int idx = blockIdx.x * 256 + threadIdx.x;
  if (idx < 64) flags[idx] = 0u;
  const float* src;
  unsigned short* dst;
  if (idx < 65536) {                       // Wi slots
    int ln = idx & 63, s = idx >> 6;
    int nsub = s & 7, s2 = s >> 3, ks = s2 & 15, bn = s2 >> 4;
    int n = bn * 128 + nsub * 16 + (ln & 15);
    int k = ks * 32 + (ln >> 4) * 8;
    src = Wi + (size_t)n * II + k;
    dst = wsWi + (size_t)idx * 8;
  } else if (idx < 196608) {               // Wh slots
    int o = idx - 65536;
    int ln = o & 63, s = o >> 6, ks = s & 31, wg = s >> 5;
    int col = wg * 16 + (ln & 15);
    int k = ks * 32 + (ln >> 4) * 8;
    src = Wh + (size_t)col * LL + k;
    dst = wsWh + (size_t)o * 8;
  } else if (idx < 204800) {               // h0 slots (row-major identity)
    int o = idx - 196608;
    src = h0 + (size_t)o * 8;
    dst = hbuf + (size_t)o * 8;
  } else {
    return;
  }
  float4 a0 = *(const float4*)src;
  float4 a1 = *(const float4*)(src + 4);
  uint4 p;
  p.x = f2bf(a0.x) | ((unsigned)f2bf(a0.y) << 16);
  p.y = f2bf(a0.z) | ((unsigned)f2bf(a0.w) << 16);
  p.z = f2bf(a1.x) | ((unsigned)f2bf(a1.y) << 16);
  p.w = f2bf(a1.z) | ((unsigned)f2bf(a1.w) << 16);
  *(uint4*)dst = p;
}

// ============================================================
// xi = x @ Wi^T + bi  -> d_out (reused as xi buffer)
// ============================================================
__global__ __launch_bounds__(256) void xi_gemm(
    const float* __restrict__ x, const float* __restrict__ bi,
    const unsigned short* __restrict__ wsWi, float* __restrict__ out) {
  __shared__ unsigned short As[8 * 64 * 8];
  __shared__ unsigned short Bs[8 * 64 * 8];
  const int tid = threadIdx.x;
  const int ln = tid & 63;
  const int wv = tid >> 6;
  const int wm = wv >> 1, wn = wv & 1;
  const int bn = blockIdx.x;
  const int Mbase = blockIdx.y * 128;
  const int Nbase = bn * 128;

  f32x4 acc[4][4] = {};

  for (int ks = 0; ks < 16; ++ks) {
    __syncthreads();
#pragma unroll
    for (int i = 0; i < 2; ++i) {
      int slot = tid + 256 * i;
      int msub = slot >> 6;
      int l2 = slot & 63;
      const float* src =
          x + (size_t)(Mbase + msub * 16 + (l2 & 15)) * II + ks * 32 + (l2 >> 4) * 8;
      float4 a0 = *(const float4*)src;
      float4 a1 = *(const float4*)(src + 4);
      uint4 p;
      p.x = f2bf(a0.x) | ((unsigned)f2bf(a0.y) << 16);
      p.y = f2bf(a0.z) | ((unsigned)f2bf(a0.w) << 16);
      p.z = f2bf(a1.x) | ((unsigned)f2bf(a1.y) << 16);
      p.w = f2bf(a1.z) | ((unsigned)f2bf(a1.w) << 16);
      *(uint4*)(As + slot * 8) = p;
      const uint4* bsrc = (const uint4*)(wsWi + (size_t)(bn * 16 + ks) * 4096) + slot;
      *(uint4*)(Bs + slot * 8) = *bsrc;
    }
    __syncthreads();
    bf16x8 af[4];
#pragma unroll
    for (int m = 0; m < 4; ++m)
      af[m] = ld_frag(As + ((wm * 4 + m) * 64 + ln) * 8);
#pragma unroll
    for (int n = 0; n < 4; ++n) {
      bf16x8 bf = ld_frag(Bs + ((wn * 4 + n) * 64 + ln) * 8);
#pragma unroll
      for (int m = 0; m < 4; ++m)
        acc[m][n] = __builtin_amdgcn_mfma_f32_16x16x32_bf16(af[m], bf, acc[m][n], 0, 0, 0);
    }
  }
#pragma unroll
  for (int n = 0; n < 4; ++n) {
    int col = Nbase + wn * 64 + n * 16 + (ln & 15);
    float bv = bi[col];
#pragma unroll
    for (int m = 0; m < 4; ++m) {
      int row0 = Mbase + wm * 64 + m * 16 + (ln >> 4) * 4;
#pragma unroll
      for (int r = 0; r < 4; ++r)
        out[(size_t)(row0 + r) * LL + col] = acc[m][n][r] + bv;
    }
  }
}

// ============================================================
// Persistent scan: 64 WGs x 4 waves. WG owns 16 cols; wave wv
// owns m-tile wv (16 batch rows) x full K=1024 -> no reduction.
// H via coalesced sc1 dwordx4 loads/stores (device-coherent,
// no fences, no L2 invalidation). xi/out plain cached (WG-local).
// ============================================================
__global__ __launch_bounds__(256) void scan_kernel(
    const unsigned short* __restrict__ wsWh, float* __restrict__ out,
    unsigned short* __restrict__ hbuf, unsigned int* __restrict__ flags) {
  __shared__ unsigned short Bfrag[32 * 64 * 8];   // 32 KiB [ks][lane][8e]
  __shared__ float xiT[4][16][20];                // 5 KiB (pad 20 for align+banks)
  __shared__ float Tt[4][16][20];                 // 5 KiB
  const int tid = threadIdx.x;
  const int ln = tid & 63;
  const int wv = tid >> 6;        // 0..3 : m-tile
  const int wg = blockIdx.x;      // 0..63: 16-col slice
  const int c16 = ln & 15;
  const int rq = ln >> 4;         // 0..3

  { // load this WG's Wh fragment slice once (32 KiB)
    const uint4* src = (const uint4*)(wsWh + (size_t)wg * 32 * 64 * 8);
    uint4* dst = (uint4*)Bfrag;
#pragma unroll
    for (int i = 0; i < 8; ++i) dst[tid + 256 * i] = src[tid + 256 * i];
  }
  __syncthreads();

  for (int t = 0; t < TT; ++t) {
    // ---- wait: all WGs published step t-1 (relaxed sc1 poll, all waves) ----
    if (t > 0) {
      unsigned f;
      do {
        f = __hip_atomic_load(flags + ln, __ATOMIC_RELAXED, __HIP_MEMORY_SCOPE_AGENT);
      } while (__all((int)f >= t) == 0);
    }
    __builtin_amdgcn_sched_barrier(0);

    const unsigned short* hcur = hbuf + (size_t)(t & 1) * 65536;

    // ---- H A-frags: 32 coalesced device-coherent 16B loads ----
    // lane reads row (wv*16 + c16), bytes ks*64 + rq*16 within the row.
    const unsigned short* hbase = hcur + (size_t)(wv * 16 + c16) * 1024 + rq * 8;
    u32x4 hv[32];
#pragma unroll
    for (int ks = 0; ks < 32; ++ks)
      asm volatile("global_load_dwordx4 %0, %1, off offset:%2 sc1"
                   : "=&v"(hv[ks]) : "v"(hbase), "i"(ks * 64) : "memory");

    // ---- xi for this wave's 16 rows (plain cached, WG-local) ----
    f32x4 xv = *(const f32x4*)(out + (size_t)t * 65536 +
                (size_t)(wv * 16 + (ln >> 2)) * 1024 + wg * 16 + (ln & 3) * 4);

    asm volatile("s_waitcnt vmcnt(0)" ::: "memory");
    __builtin_amdgcn_sched_barrier(0);
    *(f32x4*)&xiT[wv][ln >> 2][(ln & 3) * 4] = xv;

    // ---- 32 MFMAs, 2 independent chains ----
    f32x4 a0 = {}, a1 = {};
#pragma unroll
    for (int ks = 0; ks < 32; ks += 2) {
      bf16x8 b0 = ld_frag(Bfrag + (ks * 64 + ln) * 8);
      bf16x8 b1 = ld_frag(Bfrag + ((ks + 1) * 64 + ln) * 8);
      a0 = __builtin_amdgcn_mfma_f32_16x16x32_bf16(
          __builtin_bit_cast(bf16x8, hv[ks]), b0, a0, 0, 0, 0);
      a1 = __builtin_amdgcn_mfma_f32_16x16x32_bf16(
          __builtin_bit_cast(bf16x8, hv[ks + 1]), b1, a1, 0, 0, 0);
    }
    f32x4 s = a0 + a1;

    // ---- epilogue: +xi, tanh, out (plain), h (sc1) ----
    unsigned short* hnext = hbuf + (size_t)((t + 1) & 1) * 65536;
    float* outbase = out + (size_t)t * 65536 + wg * 16;
#pragma unroll
    for (int r = 0; r < 4; ++r) {
      int rl = rq * 4 + r;
      float h = tanhf(s[r] + xiT[wv][rl][c16]);
      outbase[(size_t)(wv * 16 + rl) * 1024 + c16] = h;
      Tt[wv][rl][c16] = h;
    }
    // pack bf16 row-chunks: lanes 0..31 -> row ln>>1, 8 cols (ln&1)*8
    if (ln < 32) {
      int rl = ln >> 1, cb = (ln & 1) * 8;
      const float* sp = &Tt[wv][rl][cb];
      u32x4 p;
      p[0] = f2bf(sp[0]) | ((unsigned)f2bf(sp[1]) << 16);
      p[1] = f2bf(sp[2]) | ((unsigned)f2bf(sp[3]) << 16);
      p[2] = f2bf(sp[4]) | ((unsigned)f2bf(sp[5]) << 16);
      p[3] = f2bf(sp[6]) | ((unsigned)f2bf(sp[7]) << 16);
      unsigned short* dp = hnext + (size_t)(wv * 16 + rl) * 1024 + wg * 16 + cb;
      asm volatile("global_store_dwordx4 %0, %1, off sc1"
                   :: "v"(dp), "v"(p) : "memory");
    }

    // drain all stores (h at L3, out at L2), then publish
    asm volatile("s_waitcnt vmcnt(0)" ::: "memory");
    __syncthreads();
    if (tid == 0)
      __hip_atomic_store(flags + wg, (unsigned)(t + 1), __ATOMIC_RELAXED,
                         __HIP_MEMORY_SCOPE_AGENT);
  }
}

extern "C" void kernel_launch(void* const* d_in, const int* in_sizes, int n_in,
                              void* d_out, int out_size, void* d_ws, size_t ws_size,
                              hipStream_t stream) {
  const float* x  = (const float*)d_in[0];
  const float* h0 = (const float*)d_in[1];
  const float* Wi = (const float*)d_in[2];
  const float* bi = (const float*)d_in[3];
  const float* Wh = (const float*)d_in[4];
  float* out = (float*)d_out;
  char* ws = (char*)d_ws;
  unsigned short* wsWi = (unsigned short*)(ws + WSWI_OFF);
  unsigned short* wsWh = (unsigned short*)(ws + WSWH_OFF);
  unsigned short* hbuf = (unsigned short*)(ws + HBUF_OFF);
  unsigned int* flags = (unsigned int*)(ws + FLAG_OFF);

  prep_kernel<<<800, 256, 0, stream>>>(h0, Wi, Wh, wsWi, wsWh, hbuf, flags);
  xi_gemm<<<dim3(8, 256), 256, 0, stream>>>(x, bi, wsWi, out);
  void* args[] = {(void*)&wsWh, (void*)&out, (void*)&hbuf, (void*)&flags};
  (void)hipLaunchCooperativeKernel(reinterpret_cast<void*>(scan_kernel), dim3(NWG),
                                   dim3(256), args, 0, stream);
}

// Round 6
// 1704.512 us; speedup vs baseline: 4.1695x; 2.3647x over previous
//
#include <hip/hip_runtime.h>

#define TT 512
#define BB 64
#define II 512
#define LL 1024
#define GROUPS 16
#define RPG 4            // batch rows per group
#define WPG 16           // WGs per group (64 cols each)
#define NWGS (GROUPS * WPG)

typedef __bf16 bf16x8 __attribute__((ext_vector_type(8)));
typedef float f32x4 __attribute__((ext_vector_type(4)));
typedef unsigned int u32x4 __attribute__((ext_vector_type(4)));

// ---------- workspace layout (bytes) ----------
// wsWi : Wi frag-ordered bf16 (xi_gemm)                          = 1 MiB
// wsWh2: Wh frag-ordered bf16 [16 w][4 n4][32 ks][64 l][8e]      = 2 MiB
// hbuf : ping-pong compact H  2 x [16 g][32 ks][4 kq][4 r][8e]   = 256 KiB
// flags: [16 g][64 pad] uints (first 16 per group used)          = 4 KiB
#define WSWI_OFF 0u
#define WSWH_OFF (1u << 20)
#define HBUF_OFF (3u << 20)
#define FLAG_OFF ((3u << 20) + (1u << 18))

__device__ __forceinline__ unsigned short f2bf(float f) {
  unsigned int u = __builtin_bit_cast(unsigned int, f);
  u += 0x7fffu + ((u >> 16) & 1u);   // round-to-nearest-even (inputs finite)
  return (unsigned short)(u >> 16);
}

__device__ __forceinline__ bf16x8 ld_frag(const unsigned short* p) {
  return __builtin_bit_cast(bf16x8, *(const uint4*)p);
}

// ============================================================
// prep: frag-order Wi (xi_gemm), Wh2 (scan), compact h0; zero flags.
// ============================================================
__global__ __launch_bounds__(256) void prep_kernel(
    const float* __restrict__ h0, const float* __restrict__ Wi,
    const float* __restrict__ Wh, unsigned short* __restrict__ wsWi,
    unsigned short* __restrict__ wsWh2, unsigned short* __restrict__ hbuf,
    unsigned int* __restrict__ flags) {
  int idx = blockIdx.x * 256 + threadIdx.x;
  if (idx < GROUPS * 64) flags[idx] = 0u;
  const float* src;
  unsigned short* dst;
  if (idx < 65536) {                       // Wi slots (for xi_gemm, unchanged)
    int ln = idx & 63, s = idx >> 6;
    int nsub = s & 7, s2 = s >> 3, ks = s2 & 15, bn = s2 >> 4;
    int n = bn * 128 + nsub * 16 + (ln & 15);
    int k = ks * 32 + (ln >> 4) * 8;
    src = Wi + (size_t)n * II + k;
    dst = wsWi + (size_t)idx * 8;
  } else if (idx < 196608) {               // Wh2 slots
    int o = idx - 65536;                   // [w][n4][ks][l]
    int l = o & 63, s = o >> 6;
    int ks = s & 31, s2 = s >> 5;
    int n4 = s2 & 3, w = s2 >> 2;
    int col = w * 64 + n4 * 16 + (l & 15);
    int k = ks * 32 + (l >> 4) * 8;
    src = Wh + (size_t)col * LL + k;
    dst = wsWh2 + (size_t)o * 8;
  } else if (idx < 204800) {               // h0 compact slots
    int o = idx - 196608;                  // o = ((g*32+ks)*4+kq)*4+r
    int r = o & 3, kq = (o >> 2) & 3, ks = (o >> 4) & 31, g = o >> 9;
    src = h0 + (size_t)(g * RPG + r) * LL + ks * 32 + kq * 8;
    dst = hbuf + (size_t)o * 8;
  } else {
    return;
  }
  float4 a0 = *(const float4*)src;
  float4 a1 = *(const float4*)(src + 4);
  uint4 p;
  p.x = f2bf(a0.x) | ((unsigned)f2bf(a0.y) << 16);
  p.y = f2bf(a0.z) | ((unsigned)f2bf(a0.w) << 16);
  p.z = f2bf(a1.x) | ((unsigned)f2bf(a1.y) << 16);
  p.w = f2bf(a1.z) | ((unsigned)f2bf(a1.w) << 16);
  *(uint4*)dst = p;
}

// ============================================================
// xi = x @ Wi^T + bi  -> d_out (reused as xi buffer) [unchanged]
// ============================================================
__global__ __launch_bounds__(256) void xi_gemm(
    const float* __restrict__ x, const float* __restrict__ bi,
    const unsigned short* __restrict__ wsWi, float* __restrict__ out) {
  __shared__ unsigned short As[8 * 64 * 8];
  __shared__ unsigned short Bs[8 * 64 * 8];
  const int tid = threadIdx.x;
  const int ln = tid & 63;
  const int wv = tid >> 6;
  const int wm = wv >> 1, wn = wv & 1;
  const int bn = blockIdx.x;
  const int Mbase = blockIdx.y * 128;
  const int Nbase = bn * 128;

  f32x4 acc[4][4] = {};

  for (int ks = 0; ks < 16; ++ks) {
    __syncthreads();
#pragma unroll
    for (int i = 0; i < 2; ++i) {
      int slot = tid + 256 * i;
      int msub = slot >> 6;
      int l2 = slot & 63;
      const float* src =
          x + (size_t)(Mbase + msub * 16 + (l2 & 15)) * II + ks * 32 + (l2 >> 4) * 8;
      float4 a0 = *(const float4*)src;
      float4 a1 = *(const float4*)(src + 4);
      uint4 p;
      p.x = f2bf(a0.x) | ((unsigned)f2bf(a0.y) << 16);
      p.y = f2bf(a0.z) | ((unsigned)f2bf(a0.w) << 16);
      p.z = f2bf(a1.x) | ((unsigned)f2bf(a1.y) << 16);
      p.w = f2bf(a1.z) | ((unsigned)f2bf(a1.w) << 16);
      *(uint4*)(As + slot * 8) = p;
      const uint4* bsrc = (const uint4*)(wsWi + (size_t)(bn * 16 + ks) * 4096) + slot;
      *(uint4*)(Bs + slot * 8) = *bsrc;
    }
    __syncthreads();
    bf16x8 af[4];
#pragma unroll
    for (int m = 0; m < 4; ++m)
      af[m] = ld_frag(As + ((wm * 4 + m) * 64 + ln) * 8);
#pragma unroll
    for (int n = 0; n < 4; ++n) {
      bf16x8 bf = ld_frag(Bs + ((wn * 4 + n) * 64 + ln) * 8);
#pragma unroll
      for (int m = 0; m < 4; ++m)
        acc[m][n] = __builtin_amdgcn_mfma_f32_16x16x32_bf16(af[m], bf, acc[m][n], 0, 0, 0);
    }
  }
#pragma unroll
  for (int n = 0; n < 4; ++n) {
    int col = Nbase + wn * 64 + n * 16 + (ln & 15);
    float bv = bi[col];
#pragma unroll
    for (int m = 0; m < 4; ++m) {
      int row0 = Mbase + wm * 64 + m * 16 + (ln >> 4) * 4;
#pragma unroll
      for (int r = 0; r < 4; ++r)
        out[(size_t)(row0 + r) * LL + col] = acc[m][n][r] + bv;
    }
  }
}

// ============================================================
// Batch-grouped persistent scan.
// 16 independent groups x 4 batch rows; 16 WGs/group, 64 cols each.
// Group state = 8 KB compact frag-ordered H -> 128 lines/WG/step.
// Groups never sync with each other. Within group: 1-cacheline flags,
// partial-order wait (thread waits only its 2 producers).
// ============================================================
__global__ __launch_bounds__(256) void scan_kernel(
    const unsigned short* __restrict__ wsWh2, float* __restrict__ out,
    unsigned short* __restrict__ hbuf, unsigned int* __restrict__ flags) {
  extern __shared__ char smem[];
  unsigned short* Bfrag = (unsigned short*)smem;           // 128 KiB [n4][ks][l][8e]
  unsigned short* hA    = (unsigned short*)(smem + 131072); // 8 KiB compact H
  float* xiT            = (float*)(smem + 139264);          // [4][68]
  float* hT             = (float*)(smem + 140352);          // [4][68]

  const int tid = threadIdx.x;
  const int ln = tid & 63;
  const int wv = tid >> 6;                 // 0..3 : n4 (16-col subtile)
  const int g = blockIdx.x >> 4;           // group
  const int w = blockIdx.x & 15;           // col-slice within group
  const int kq = ln >> 4, rdup = ln & 3;
  const int xr = tid >> 4, xj = (tid & 15) * 4;   // for tid<64 xi/out tiles

  { // load this WG's Wh slice (128 KiB) into LDS once
    const uint4* src = (const uint4*)(wsWh2 + (size_t)w * 65536);
    uint4* dst = (uint4*)Bfrag;
#pragma unroll
    for (int i = 0; i < 32; ++i) dst[tid + 256 * i] = src[tid + 256 * i];
  }
  __syncthreads();

  const unsigned int* gflags = flags + g * 64;
  const int pa = tid >> 5;                 // producer of chunk tid
  const int pb = 8 + (tid >> 5);           // producer of chunk tid+256

  for (int t = 0; t < TT; ++t) {
    // xi prefetch (plain cached; independent of h)
    f32x4 xv = {};
    if (tid < 64)
      xv = *(const f32x4*)(out + (size_t)t * 65536 +
                           (size_t)(g * RPG + xr) * LL + w * 64 + xj);

    // ---- wait (partial order): only this thread's 2 producers ----
    if (t > 0) {
      unsigned f0, f1;
      do {
        f0 = __hip_atomic_load(gflags + pa, __ATOMIC_RELAXED, __HIP_MEMORY_SCOPE_AGENT);
        f1 = __hip_atomic_load(gflags + pb, __ATOMIC_RELAXED, __HIP_MEMORY_SCOPE_AGENT);
      } while (__all((int)f0 >= t && (int)f1 >= t) == 0);
    }
    __builtin_amdgcn_sched_barrier(0);

    // ---- gather group H: 8 KB, 2 x 16B per thread, sc1 ----
    const unsigned short* hcur = hbuf + (size_t)(t & 1) * 65536 + g * 4096;
    u32x4 hv0, hv1;
    const unsigned short* a0p = hcur + tid * 8;
    const unsigned short* a1p = hcur + (tid + 256) * 8;
    asm volatile("global_load_dwordx4 %0, %1, off sc1"
                 : "=&v"(hv0) : "v"(a0p) : "memory");
    asm volatile("global_load_dwordx4 %0, %1, off sc1"
                 : "=&v"(hv1) : "v"(a1p) : "memory");
    asm volatile("s_waitcnt vmcnt(0)" ::: "memory");
    __builtin_amdgcn_sched_barrier(0);
    *(u32x4*)(hA + tid * 8) = hv0;
    *(u32x4*)(hA + (tid + 256) * 8) = hv1;
    if (tid < 64) *(f32x4*)&xiT[xr * 68 + xj] = xv;
    __syncthreads();

    // ---- MFMA: this wave's 16 cols x K=1024, 2 chains ----
    const unsigned short* Bb = Bfrag + wv * 16384;
    f32x4 c0 = {}, c1 = {};
#pragma unroll
    for (int ks = 0; ks < 32; ks += 2) {
      bf16x8 A0 = ld_frag(hA + (ks * 16 + kq * 4 + rdup) * 8);
      bf16x8 A1 = ld_frag(hA + ((ks + 1) * 16 + kq * 4 + rdup) * 8);
      bf16x8 B0 = ld_frag(Bb + (ks * 64 + ln) * 8);
      bf16x8 B1 = ld_frag(Bb + ((ks + 1) * 64 + ln) * 8);
      c0 = __builtin_amdgcn_mfma_f32_16x16x32_bf16(A0, B0, c0, 0, 0, 0);
      c1 = __builtin_amdgcn_mfma_f32_16x16x32_bf16(A1, B1, c1, 0, 0, 0);
    }
    f32x4 s = c0 + c1;

    // ---- epilogue: rows 0..3 live in lanes 0..15 (regs = rows) ----
    if (ln < 16) {
      int j = wv * 16 + ln;
#pragma unroll
      for (int r = 0; r < 4; ++r)
        hT[r * 68 + j] = tanhf(s[r] + xiT[r * 68 + j]);
    }
    __syncthreads();

    // ---- out fp32 (plain) + compact h bf16 (sc1, one 512B run/WG) ----
    unsigned short* hnext = hbuf + (size_t)((t + 1) & 1) * 65536 + g * 4096;
    if (tid < 64) {
      f32x4 o = *(const f32x4*)&hT[xr * 68 + xj];
      *(f32x4*)(out + (size_t)t * 65536 +
                (size_t)(g * RPG + xr) * LL + w * 64 + xj) = o;
    }
    if (tid < 32) {
      int r = tid & 3, kq2 = (tid >> 2) & 3, sb = tid >> 4;
      const float* sp = &hT[r * 68 + sb * 32 + kq2 * 8];
      u32x4 p;
      p[0] = f2bf(sp[0]) | ((unsigned)f2bf(sp[1]) << 16);
      p[1] = f2bf(sp[2]) | ((unsigned)f2bf(sp[3]) << 16);
      p[2] = f2bf(sp[4]) | ((unsigned)f2bf(sp[5]) << 16);
      p[3] = f2bf(sp[6]) | ((unsigned)f2bf(sp[7]) << 16);
      unsigned short* dp = hnext + ((size_t)((w * 2 + sb) * 16 + kq2 * 4 + r)) * 8;
      asm volatile("global_store_dwordx4 %0, %1, off sc1"
                   :: "v"(dp), "v"(p) : "memory");
    }
    asm volatile("s_waitcnt vmcnt(0)" ::: "memory");
    __syncthreads();
    if (tid == 0)
      __hip_atomic_store(flags + g * 64 + w, (unsigned)(t + 1), __ATOMIC_RELAXED,
                         __HIP_MEMORY_SCOPE_AGENT);
  }
}

extern "C" void kernel_launch(void* const* d_in, const int* in_sizes, int n_in,
                              void* d_out, int out_size, void* d_ws, size_t ws_size,
                              hipStream_t stream) {
  const float* x  = (const float*)d_in[0];
  const float* h0 = (const float*)d_in[1];
  const float* Wi = (const float*)d_in[2];
  const float* bi = (const float*)d_in[3];
  const float* Wh = (const float*)d_in[4];
  float* out = (float*)d_out;
  char* ws = (char*)d_ws;
  unsigned short* wsWi  = (unsigned short*)(ws + WSWI_OFF);
  unsigned short* wsWh2 = (unsigned short*)(ws + WSWH_OFF);
  unsigned short* hbuf  = (unsigned short*)(ws + HBUF_OFF);
  unsigned int* flags   = (unsigned int*)(ws + FLAG_OFF);

  prep_kernel<<<800, 256, 0, stream>>>(h0, Wi, Wh, wsWi, wsWh2, hbuf, flags);
  xi_gemm<<<dim3(8, 256), 256, 0, stream>>>(x, bi, wsWi, out);
  void* args[] = {(void*)&wsWh2, (void*)&out, (void*)&hbuf, (void*)&flags};
  (void)hipLaunchCooperativeKernel(reinterpret_cast<void*>(scan_kernel),
                                   dim3(NWGS), dim3(256), args, 141440, stream);
}